// Round 8
// baseline (549.355 us; speedup 1.0000x reference)
//
#include <hip/hip_runtime.h>
#include <hip/hip_bf16.h>

typedef __bf16 bf16;
typedef __attribute__((ext_vector_type(8))) __bf16 bf16x8;
typedef __attribute__((ext_vector_type(2))) __bf16 bf16x2;
typedef __attribute__((ext_vector_type(4))) float f32x4;
typedef __attribute__((ext_vector_type(16))) float f32x16;
typedef __attribute__((ext_vector_type(4))) unsigned int u32x4;

#define DIMV 512
#define NH 8
#define HDIM 64
#define SEQ 4096
#define BB_ 2
#define M_TOT (BB_ * SEQ)   /* 8192 */
#define NQKV 1536

static __device__ __forceinline__ f32x4 mfma16(bf16x8 a, bf16x8 b, f32x4 c) {
  return __builtin_amdgcn_mfma_f32_16x16x32_bf16(a, b, c, 0, 0, 0);
}
static __device__ __forceinline__ f32x16 mfma32(bf16x8 a, bf16x8 b, f32x16 c) {
  return __builtin_amdgcn_mfma_f32_32x32x16_bf16(a, b, c, 0, 0, 0);
}
static __device__ __forceinline__ unsigned pk2(float a, float b) {
  bf16x2 t; t[0] = (bf16)a; t[1] = (bf16)b;
  return __builtin_bit_cast(unsigned, t);
}
// v_permlane32_swap_b32: a[hi lanes] <-> b[lo lanes] (CDNA4)
static __device__ __forceinline__ void swap32(unsigned& a, unsigned& b) {
  asm("v_permlane32_swap_b32 %0, %1" : "+v"(a), "+v"(b));
}

// ---------------------------------------------------------------------------
// Kernel 0: weight transpose->bf16, x->bf16, mask->bias floats
// ---------------------------------------------------------------------------
__global__ void prep_w(const float* __restrict__ Wqkv, const float* __restrict__ Wproj,
                       const float* __restrict__ x, const int* __restrict__ mask,
                       bf16* __restrict__ WqkvT, bf16* __restrict__ WprojT,
                       bf16* __restrict__ xb, float* __restrict__ BBias) {
  const int t1 = DIMV * NQKV;            // WqkvT
  const int t2 = t1 + DIMV * DIMV;       // WprojT
  const int t3 = t2 + M_TOT * DIMV;      // xb
  const int t4 = t3 + BB_ * SEQ;         // bias
  for (int i = blockIdx.x * blockDim.x + threadIdx.x; i < t4;
       i += gridDim.x * blockDim.x) {
    if (i < t1) {
      int n = i / DIMV, k = i - n * DIMV;
      WqkvT[i] = (bf16)Wqkv[(size_t)k * NQKV + n];
    } else if (i < t2) {
      int o = i - t1;
      int n = o / DIMV, k = o - n * DIMV;
      WprojT[o] = (bf16)Wproj[(size_t)k * DIMV + n];
    } else if (i < t3) {
      int o = i - t2;
      xb[o] = (bf16)x[o];
    } else {
      int o = i - t3;
      BBias[o] = mask[o] ? -1.0e30f : 0.0f;
    }
  }
}

// ---------------------------------------------------------------------------
// Kernel 1: QKV = x @ Wqkv + b, fused RoPE, scatter to Q,K [bh][l][d], VT [bh][d][l]
// ---------------------------------------------------------------------------
__global__ __launch_bounds__(256) void gemm1_qkv_rope(
    const bf16* __restrict__ xb, const bf16* __restrict__ WT,
    const float* __restrict__ bqkv, const float* __restrict__ cosT,
    const float* __restrict__ sinT, bf16* __restrict__ Q,
    bf16* __restrict__ Kd, bf16* __restrict__ VT) {
  const int tid = threadIdx.x;
  const int wave = tid >> 6, lane = tid & 63;
  const int l16 = lane & 15, lg = lane >> 4;
  const int Mbase = blockIdx.x * 128 + (wave >> 1) * 64;
  const int Nbase = blockIdx.y * 128 + (wave & 1) * 64;

  f32x4 acc[4][4] = {};
  for (int k0 = 0; k0 < DIMV; k0 += 32) {
    const int kb = k0 + lg * 8;
    bf16x8 af[4], bfr[4];
#pragma unroll
    for (int r = 0; r < 4; ++r) {
      af[r] = *reinterpret_cast<const bf16x8*>(
          xb + (size_t)(Mbase + r * 16 + l16) * DIMV + kb);
      bfr[r] = *reinterpret_cast<const bf16x8*>(
          WT + (size_t)(Nbase + r * 16 + l16) * DIMV + kb);
    }
#pragma unroll
    for (int mr = 0; mr < 4; ++mr)
#pragma unroll
      for (int nr = 0; nr < 4; ++nr)
        acc[mr][nr] = mfma16(af[mr], bfr[nr], acc[mr][nr]);
  }

#pragma unroll
  for (int mr = 0; mr < 4; ++mr) {
#pragma unroll
    for (int nr = 0; nr < 4; ++nr) {
#pragma unroll
      for (int j = 0; j < 4; ++j) {
        const int n = Nbase + nr * 16 + l16;
        const int m = Mbase + mr * 16 + lg * 4 + j;
        const int g = n >> 9, rem = n & 511, h = rem >> 6, d = rem & 63;
        const int b = m >> 12, l = m & 4095;
        float val = acc[mr][nr][j] + bqkv[n];
        if (g == 2) {
          VT[((size_t)(b * NH + h) * HDIM + d) * SEQ + l] = (bf16)val;
        } else {
          float pairval = acc[mr][nr ^ 2][j] + bqkv[n ^ 32];
          float c = cosT[l * HDIM + d], s = sinT[l * HDIM + d];
          float o = (d < 32) ? (val * c - pairval * s) : (val * c + pairval * s);
          bf16* dst = (g == 0) ? Q : Kd;
          dst[((size_t)(b * NH + h) * SEQ + l) * HDIM + d] = (bf16)o;
        }
      }
    }
  }
}

// ---------------------------------------------------------------------------
// Kernel 2: flash attention, swapped-QK^T 32x32, no max tracking.
// Grid (SEQ/32, B*H), 256 thr.  All 4 waves share ONE 32-row q-tile and
// split the 4096 keys into 1024-key ranges (occupancy: 8192 waves = 100%
// of wave slots vs 25% before).  Partial O/l merged via LDS atomics.
// ---------------------------------------------------------------------------
__global__ __launch_bounds__(256) void attn_kernel(
    const bf16* __restrict__ Q, const bf16* __restrict__ Kd,
    const bf16* __restrict__ VT, const float* __restrict__ BBias,
    bf16* __restrict__ AO) {
  __shared__ __align__(16) float O_lds[32][64];   // 8 KiB accumulator
  __shared__ float L_lds[32];
  const int tid = threadIdx.x;
  const int wv = tid >> 6, lane = tid & 63;
  const int l32 = lane & 31, hi = lane >> 5;
  const int bh = blockIdx.y, b = bh >> 3, h = bh & 7;
  const int qb = blockIdx.x * 32;
  const float C1 = 0.125f * 1.44269504f;  // 1/sqrt(64) * log2(e)

  // zero the block accumulator
  reinterpret_cast<f32x4*>(O_lds)[tid * 2]     = f32x4{};
  reinterpret_cast<f32x4*>(O_lds)[tid * 2 + 1] = f32x4{};
  if (tid < 32) L_lds[tid] = 0.0f;
  __syncthreads();

  // Q B-frags: qfrag[w] holds Q[qb + l32][16w + 8hi + j] (same for all waves)
  const bf16* qrow = Q + ((size_t)bh * SEQ + qb + l32) * HDIM + 8 * hi;
  bf16x8 qfrag[4];
#pragma unroll
  for (int w = 0; w < 4; ++w)
    qfrag[w] = *reinterpret_cast<const bf16x8*>(qrow + 16 * w);

  const bf16* krow = Kd + ((size_t)bh * SEQ + l32) * HDIM + 8 * hi;
  const bf16* vrow0 = VT + ((size_t)bh * HDIM + l32) * SEQ + 8 * hi;
  const bf16* vrow1 = VT + ((size_t)bh * HDIM + 32 + l32) * SEQ + 8 * hi;
  const float* bbp = BBias + b * SEQ + 4 * hi;

  f32x16 o0 = {}, o1 = {};
  f32x4 lacc = {};

  const int kbeg = wv * (SEQ / 4), kend = kbeg + SEQ / 4;
  for (int kb = kbeg; kb < kend; kb += 32) {
    // ---- S^T[key][q]: A = K rows (m=key), B = Q rows (n=q) ----------------
    f32x16 S = {};
#pragma unroll
    for (int w = 0; w < 4; ++w) {
      bf16x8 kf = *reinterpret_cast<const bf16x8*>(krow + (size_t)kb * HDIM + 16 * w);
      S = mfma32(kf, qfrag[w], S);
    }
    // lane reg r -> key kb + (r&3) + 8*(r>>2) + 4*hi, q = qb + l32

    // ---- e = exp2(s*C1 + bias[key]) (bias=-1e30 for masked -> e=0) --------
    float e[16];
#pragma unroll
    for (int g = 0; g < 4; ++g) {
      f32x4 bb = *reinterpret_cast<const f32x4*>(bbp + kb + 8 * g);
#pragma unroll
      for (int j = 0; j < 4; ++j) {
        float ev = __builtin_amdgcn_exp2f(fmaf(S[g * 4 + j], C1, bb[j]));
        e[g * 4 + j] = ev;
        lacc[j] += ev;
      }
    }

    // ---- pack P -> PV A-frags (q = l32 rows, key = hi*8+j within window) --
    unsigned c0 = pk2(e[0], e[1]),  c1 = pk2(e[2], e[3]);
    unsigned c2 = pk2(e[4], e[5]),  c3 = pk2(e[6], e[7]);
    unsigned c4 = pk2(e[8], e[9]),  c5 = pk2(e[10], e[11]);
    unsigned c6 = pk2(e[12], e[13]), c7 = pk2(e[14], e[15]);
    swap32(c0, c2); swap32(c1, c3);   // window 0: keys kb..kb+15
    swap32(c4, c6); swap32(c5, c7);   // window 1: keys kb+16..kb+31
    u32x4 u0 = {c0, c1, c2, c3}, u1 = {c4, c5, c6, c7};
    bf16x8 pa0 = __builtin_bit_cast(bf16x8, u0);
    bf16x8 pa1 = __builtin_bit_cast(bf16x8, u1);

    // ---- PV: A = P (m=q), B = V (n=d) via VT rows -------------------------
    bf16x8 v00 = *reinterpret_cast<const bf16x8*>(vrow0 + kb);
    bf16x8 v01 = *reinterpret_cast<const bf16x8*>(vrow0 + kb + 16);
    bf16x8 v10 = *reinterpret_cast<const bf16x8*>(vrow1 + kb);
    bf16x8 v11 = *reinterpret_cast<const bf16x8*>(vrow1 + kb + 16);
    o0 = mfma32(pa0, v00, o0);
    o0 = mfma32(pa1, v01, o0);
    o1 = mfma32(pa0, v10, o1);
    o1 = mfma32(pa1, v11, o1);
  }

  // ---- merge partials into LDS -------------------------------------------
  float ls = lacc[0] + lacc[1] + lacc[2] + lacc[3];
  ls += __shfl_xor(ls, 32, 64);     // both hi halves now hold this wave's sum
  if (hi == 0) atomicAdd(&L_lds[l32], ls);
#pragma unroll
  for (int r = 0; r < 16; ++r) {
    const int q = (r & 3) + 8 * (r >> 2) + 4 * hi;
    atomicAdd(&O_lds[q][l32], o0[r]);
    atomicAdd(&O_lds[q][32 + l32], o1[r]);
  }
  __syncthreads();

  // ---- normalize + write: thread -> (q = tid>>3, d = (tid&7)*8 .. +8) ----
  {
    const int q = tid >> 3, dd = (tid & 7) * 8;
    const float inv = 1.0f / L_lds[q];
    f32x4 a = *reinterpret_cast<const f32x4*>(&O_lds[q][dd]);
    f32x4 c = *reinterpret_cast<const f32x4*>(&O_lds[q][dd + 4]);
    bf16x8 ov;
#pragma unroll
    for (int i = 0; i < 4; ++i) {
      ov[i]     = (bf16)(a[i] * inv);
      ov[i + 4] = (bf16)(c[i] * inv);
    }
    *reinterpret_cast<bf16x8*>(
        AO + ((size_t)b * SEQ + qb + q) * DIMV + h * HDIM + dd) = ov;
  }
}

// ---------------------------------------------------------------------------
// Kernel 3: y = AO @ Wproj + bproj + x  -> d_out (fp32)
// ---------------------------------------------------------------------------
__global__ __launch_bounds__(256) void gemm2_proj(
    const bf16* __restrict__ AO, const bf16* __restrict__ WT,
    const float* __restrict__ bproj, const float* __restrict__ x,
    float* __restrict__ Y) {
  const int tid = threadIdx.x;
  const int wave = tid >> 6, lane = tid & 63;
  const int l16 = lane & 15, lg = lane >> 4;
  const int Mbase = blockIdx.x * 128 + (wave >> 1) * 64;
  const int Nbase = blockIdx.y * 128 + (wave & 1) * 64;

  f32x4 acc[4][4] = {};
  for (int k0 = 0; k0 < DIMV; k0 += 32) {
    const int kb = k0 + lg * 8;
    bf16x8 af[4], bfr[4];
#pragma unroll
    for (int r = 0; r < 4; ++r) {
      af[r] = *reinterpret_cast<const bf16x8*>(
          AO + (size_t)(Mbase + r * 16 + l16) * DIMV + kb);
      bfr[r] = *reinterpret_cast<const bf16x8*>(
          WT + (size_t)(Nbase + r * 16 + l16) * DIMV + kb);
    }
#pragma unroll
    for (int mr = 0; mr < 4; ++mr)
#pragma unroll
      for (int nr = 0; nr < 4; ++nr)
        acc[mr][nr] = mfma16(af[mr], bfr[nr], acc[mr][nr]);
  }
#pragma unroll
  for (int mr = 0; mr < 4; ++mr)
#pragma unroll
    for (int nr = 0; nr < 4; ++nr)
#pragma unroll
      for (int j = 0; j < 4; ++j) {
        const int n = Nbase + nr * 16 + l16;
        const int m = Mbase + mr * 16 + lg * 4 + j;
        Y[(size_t)m * DIMV + n] = acc[mr][nr][j] + bproj[n] + x[(size_t)m * DIMV + n];
      }
}

// ---------------------------------------------------------------------------
// Kernel 4: in-place LayerNorm over rows of 512
// ---------------------------------------------------------------------------
__global__ __launch_bounds__(128) void ln_kernel(float* __restrict__ Y,
                                                 const float* __restrict__ gamma,
                                                 const float* __restrict__ beta) {
  const int row = blockIdx.x, tid = threadIdx.x;
  float* rp = Y + (size_t)row * DIMV;
  f32x4 v = *reinterpret_cast<const f32x4*>(rp + tid * 4);
  float s = v[0] + v[1] + v[2] + v[3];
  float q = v[0] * v[0] + v[1] * v[1] + v[2] * v[2] + v[3] * v[3];
#pragma unroll
  for (int off = 1; off < 64; off <<= 1) {
    s += __shfl_xor(s, off, 64);
    q += __shfl_xor(q, off, 64);
  }
  __shared__ float sh[4];
  if ((tid & 63) == 0) { sh[(tid >> 6) * 2] = s; sh[(tid >> 6) * 2 + 1] = q; }
  __syncthreads();
  const float ts = sh[0] + sh[2], tq = sh[1] + sh[3];
  const float mu = ts * (1.0f / DIMV);
  const float var = tq * (1.0f / DIMV) - mu * mu;
  const float rs = rsqrtf(var + 1e-5f);
  f32x4 ov;
#pragma unroll
  for (int i = 0; i < 4; ++i) {
    const int c = tid * 4 + i;
    ov[i] = (v[i] - mu) * rs * gamma[c] + beta[c];
  }
  *reinterpret_cast<f32x4*>(rp + tid * 4) = ov;
}

// ---------------------------------------------------------------------------
extern "C" void kernel_launch(void* const* d_in, const int* in_sizes, int n_in,
                              void* d_out, int out_size, void* d_ws, size_t ws_size,
                              hipStream_t stream) {
  const float* x      = (const float*)d_in[0];
  const int*   pmask  = (const int*)d_in[1];
  const float* Wqkv   = (const float*)d_in[2];
  const float* bqkv   = (const float*)d_in[3];
  const float* Wproj  = (const float*)d_in[4];
  const float* bproj  = (const float*)d_in[5];
  const float* gamma  = (const float*)d_in[6];
  const float* beta   = (const float*)d_in[7];
  const float* cosT   = (const float*)d_in[8];
  const float* sinT   = (const float*)d_in[9];
  float* out = (float*)d_out;

  char* ws = (char*)d_ws;
  const size_t MB = 1048576;
  bf16* WqkvT  = (bf16*)(ws);                       // 1.5 MiB
  bf16* WprojT = (bf16*)(ws + 3 * MB / 2);          // 0.5 MiB
  bf16* Q      = (bf16*)(ws + 2 * MB);              // 8 MiB
  bf16* Kd     = (bf16*)(ws + 10 * MB);             // 8 MiB
  bf16* VT     = (bf16*)(ws + 18 * MB);             // 8 MiB
  bf16* AO     = (bf16*)(ws + 26 * MB);             // 8 MiB (aliased with xb)
  bf16* xb     = AO;                                // xb dead before AO written
  float* BBias = (float*)(ws + 34 * MB);            // 32 KiB

  prep_w<<<2048, 256, 0, stream>>>(Wqkv, Wproj, x, pmask, WqkvT, WprojT, xb, BBias);
  gemm1_qkv_rope<<<dim3(M_TOT / 128, NQKV / 128), 256, 0, stream>>>(
      xb, WqkvT, bqkv, cosT, sinT, Q, Kd, VT);
  attn_kernel<<<dim3(SEQ / 32, BB_ * NH), 256, 0, stream>>>(Q, Kd, VT, BBias, AO);
  gemm2_proj<<<dim3(M_TOT / 128, DIMV / 128), 256, 0, stream>>>(AO, WprojT, bproj, x, out);
  ln_kernel<<<M_TOT, 128, 0, stream>>>(out, gamma, beta);
}

// Round 10
// 299.570 us; speedup vs baseline: 1.8338x; 1.8338x over previous
//
#include <hip/hip_runtime.h>
#include <hip/hip_bf16.h>

typedef __bf16 bf16;
typedef __attribute__((ext_vector_type(8))) __bf16 bf16x8;
typedef __attribute__((ext_vector_type(2))) __bf16 bf16x2;
typedef __attribute__((ext_vector_type(4))) float f32x4;
typedef __attribute__((ext_vector_type(16))) float f32x16;
typedef __attribute__((ext_vector_type(4))) unsigned int u32x4;

#define DIMV 512
#define NH 8
#define HDIM 64
#define SEQ 4096
#define BB_ 2
#define M_TOT (BB_ * SEQ)   /* 8192 */
#define NQKV 1536
#define KVBLK 64            /* keys per LDS tile */

static __device__ __forceinline__ f32x4 mfma16(bf16x8 a, bf16x8 b, f32x4 c) {
  return __builtin_amdgcn_mfma_f32_16x16x32_bf16(a, b, c, 0, 0, 0);
}
static __device__ __forceinline__ f32x16 mfma32(bf16x8 a, bf16x8 b, f32x16 c) {
  return __builtin_amdgcn_mfma_f32_32x32x16_bf16(a, b, c, 0, 0, 0);
}
static __device__ __forceinline__ unsigned pk2(float a, float b) {
  bf16x2 t; t[0] = (bf16)a; t[1] = (bf16)b;
  return __builtin_bit_cast(unsigned, t);
}
// v_permlane32_swap_b32: a[hi lanes] <-> b[lo lanes] (CDNA4)
static __device__ __forceinline__ void swap32(unsigned& a, unsigned& b) {
  asm("v_permlane32_swap_b32 %0, %1" : "+v"(a), "+v"(b));
}
// XOR swizzle within a 128-B LDS row: spreads column-slices across banks
static __device__ __forceinline__ int swz(int row, int byteoff) {
  return byteoff ^ ((row & 7) << 4);
}

// ---------------------------------------------------------------------------
// Kernel 0: weight transpose->bf16, x->bf16, mask->bias floats
// ---------------------------------------------------------------------------
__global__ void prep_w(const float* __restrict__ Wqkv, const float* __restrict__ Wproj,
                       const float* __restrict__ x, const int* __restrict__ mask,
                       bf16* __restrict__ WqkvT, bf16* __restrict__ WprojT,
                       bf16* __restrict__ xb, float* __restrict__ BBias) {
  const int t1 = DIMV * NQKV;            // WqkvT
  const int t2 = t1 + DIMV * DIMV;       // WprojT
  const int t3 = t2 + M_TOT * DIMV;      // xb
  const int t4 = t3 + BB_ * SEQ;         // bias
  for (int i = blockIdx.x * blockDim.x + threadIdx.x; i < t4;
       i += gridDim.x * blockDim.x) {
    if (i < t1) {
      int n = i / DIMV, k = i - n * DIMV;
      WqkvT[i] = (bf16)Wqkv[(size_t)k * NQKV + n];
    } else if (i < t2) {
      int o = i - t1;
      int n = o / DIMV, k = o - n * DIMV;
      WprojT[o] = (bf16)Wproj[(size_t)k * DIMV + n];
    } else if (i < t3) {
      int o = i - t2;
      xb[o] = (bf16)x[o];
    } else {
      int o = i - t3;
      BBias[o] = mask[o] ? -1.0e30f : 0.0f;
    }
  }
}

// ---------------------------------------------------------------------------
// Kernel 1: QKV = x @ Wqkv + b, fused RoPE, scatter to Q,K [bh][l][d], VT [bh][d][l]
// ---------------------------------------------------------------------------
__global__ __launch_bounds__(256) void gemm1_qkv_rope(
    const bf16* __restrict__ xb, const bf16* __restrict__ WT,
    const float* __restrict__ bqkv, const float* __restrict__ cosT,
    const float* __restrict__ sinT, bf16* __restrict__ Q,
    bf16* __restrict__ Kd, bf16* __restrict__ VT) {
  const int tid = threadIdx.x;
  const int wave = tid >> 6, lane = tid & 63;
  const int l16 = lane & 15, lg = lane >> 4;
  const int Mbase = blockIdx.x * 128 + (wave >> 1) * 64;
  const int Nbase = blockIdx.y * 128 + (wave & 1) * 64;

  f32x4 acc[4][4] = {};
  for (int k0 = 0; k0 < DIMV; k0 += 32) {
    const int kb = k0 + lg * 8;
    bf16x8 af[4], bfr[4];
#pragma unroll
    for (int r = 0; r < 4; ++r) {
      af[r] = *reinterpret_cast<const bf16x8*>(
          xb + (size_t)(Mbase + r * 16 + l16) * DIMV + kb);
      bfr[r] = *reinterpret_cast<const bf16x8*>(
          WT + (size_t)(Nbase + r * 16 + l16) * DIMV + kb);
    }
#pragma unroll
    for (int mr = 0; mr < 4; ++mr)
#pragma unroll
      for (int nr = 0; nr < 4; ++nr)
        acc[mr][nr] = mfma16(af[mr], bfr[nr], acc[mr][nr]);
  }

#pragma unroll
  for (int mr = 0; mr < 4; ++mr) {
#pragma unroll
    for (int nr = 0; nr < 4; ++nr) {
#pragma unroll
      for (int j = 0; j < 4; ++j) {
        const int n = Nbase + nr * 16 + l16;
        const int m = Mbase + mr * 16 + lg * 4 + j;
        const int g = n >> 9, rem = n & 511, h = rem >> 6, d = rem & 63;
        const int b = m >> 12, l = m & 4095;
        float val = acc[mr][nr][j] + bqkv[n];
        if (g == 2) {
          VT[((size_t)(b * NH + h) * HDIM + d) * SEQ + l] = (bf16)val;
        } else {
          float pairval = acc[mr][nr ^ 2][j] + bqkv[n ^ 32];
          float c = cosT[l * HDIM + d], s = sinT[l * HDIM + d];
          float o = (d < 32) ? (val * c - pairval * s) : (val * c + pairval * s);
          bf16* dst = (g == 0) ? Q : Kd;
          dst[((size_t)(b * NH + h) * SEQ + l) * HDIM + d] = (bf16)o;
        }
      }
    }
  }
}

// ---------------------------------------------------------------------------
// Kernel 2: flash attention, swapped-QK^T 32x32, no max tracking.
// Grid (SEQ/128, B*H), 4 waves x 32-q tiles.  K/V staged per 64-key tile
// through XOR-swizzled, double-buffered LDS with coalesced global loads
// (issue-early / write-late).  MFMA + softmax math identical to round 7.
// ---------------------------------------------------------------------------
__global__ __launch_bounds__(256) void attn_kernel(
    const bf16* __restrict__ Q, const bf16* __restrict__ Kd,
    const bf16* __restrict__ VT, const float* __restrict__ BBias,
    bf16* __restrict__ AO) {
  // [buf][K=0/V=1][64 rows][128 B]  = 32 KiB
  __shared__ __align__(16) char kv_lds[2][2][KVBLK * 128];
  __shared__ __align__(16) float lsum_lds[4][32];

  const int tid = threadIdx.x;
  const int wv = tid >> 6, lane = tid & 63;
  const int l32 = lane & 31, hi = lane >> 5;
  const int bh = blockIdx.y, b = bh >> 3, h = bh & 7;
  const int qb = blockIdx.x * 128 + wv * 32;
  const float C1 = 0.125f * 1.44269504f;  // 1/sqrt(64) * log2(e)

  // Q B-frags: qfrag[w] holds Q[qb + l32][16w + 8hi + j]
  const bf16* qrow = Q + ((size_t)bh * SEQ + qb + l32) * HDIM + 8 * hi;
  bf16x8 qfrag[4];
#pragma unroll
  for (int w = 0; w < 4; ++w)
    qfrag[w] = *reinterpret_cast<const bf16x8*>(qrow + 16 * w);

  // staging geometry: chunk c in [0,512): row = c>>3, slot = c&7 (16 B each)
  const bf16* Kbase = Kd + (size_t)bh * SEQ * HDIM;   // K[key][d] row = 128 B
  const bf16* Vbase = VT + (size_t)bh * HDIM * SEQ;   // V[d][key]
  const int c0 = tid, c1 = tid + 256;
  const int kr0 = c0 >> 3, ks0 = c0 & 7;
  const int kr1 = c1 >> 3, ks1 = c1 & 7;

  const float* bbp = BBias + b * SEQ + 4 * hi;

  f32x16 o0 = {}, o1 = {};
  f32x4 lacc = {};

  bf16x8 kreg0, kreg1, vreg0, vreg1;
  // ---- prologue: stage tile 0 --------------------------------------------
  {
    kreg0 = *reinterpret_cast<const bf16x8*>(Kbase + (size_t)kr0 * HDIM + ks0 * 8);
    kreg1 = *reinterpret_cast<const bf16x8*>(Kbase + (size_t)kr1 * HDIM + ks1 * 8);
    vreg0 = *reinterpret_cast<const bf16x8*>(Vbase + (size_t)kr0 * SEQ + ks0 * 8);
    vreg1 = *reinterpret_cast<const bf16x8*>(Vbase + (size_t)kr1 * SEQ + ks1 * 8);
    char* kb_ = kv_lds[0][0]; char* vb_ = kv_lds[0][1];
    *reinterpret_cast<bf16x8*>(kb_ + kr0 * 128 + swz(kr0, ks0 * 16)) = kreg0;
    *reinterpret_cast<bf16x8*>(kb_ + kr1 * 128 + swz(kr1, ks1 * 16)) = kreg1;
    *reinterpret_cast<bf16x8*>(vb_ + kr0 * 128 + swz(kr0, ks0 * 16)) = vreg0;
    *reinterpret_cast<bf16x8*>(vb_ + kr1 * 128 + swz(kr1, ks1 * 16)) = vreg1;
  }
  __syncthreads();

  const int NT = SEQ / KVBLK;
  for (int t = 0; t < NT; ++t) {
    const int cur = t & 1;
    const int kb = t * KVBLK;
    // ---- issue next tile's global loads early (T14) -----------------------
    if (t + 1 < NT) {
      const int nkb = kb + KVBLK;
      kreg0 = *reinterpret_cast<const bf16x8*>(Kbase + (size_t)(nkb + kr0) * HDIM + ks0 * 8);
      kreg1 = *reinterpret_cast<const bf16x8*>(Kbase + (size_t)(nkb + kr1) * HDIM + ks1 * 8);
      vreg0 = *reinterpret_cast<const bf16x8*>(Vbase + (size_t)kr0 * SEQ + nkb + ks0 * 8);
      vreg1 = *reinterpret_cast<const bf16x8*>(Vbase + (size_t)kr1 * SEQ + nkb + ks1 * 8);
    }

    // ---- compute the two 32-key groups of this tile -----------------------
    const char* kt = kv_lds[cur][0];
    const char* vt = kv_lds[cur][1];
#pragma unroll
    for (int g = 0; g < 2; ++g) {
      // S^T = K·Q^T over 32 keys
      f32x16 S = {};
#pragma unroll
      for (int w = 0; w < 4; ++w) {
        const int row = 32 * g + l32;
        bf16x8 kf = *reinterpret_cast<const bf16x8*>(
            kt + row * 128 + swz(row, 32 * w + 16 * hi));
        S = mfma32(kf, qfrag[w], S);
      }
      // e = exp2(s*C1 + bias[key]); key = kb + 32g + 8*(r>>2) + 4hi + (r&3)
      float e[16];
#pragma unroll
      for (int g4 = 0; g4 < 4; ++g4) {
        f32x4 bb = *reinterpret_cast<const f32x4*>(bbp + kb + 32 * g + 8 * g4);
#pragma unroll
        for (int j = 0; j < 4; ++j) {
          float ev = __builtin_amdgcn_exp2f(fmaf(S[g4 * 4 + j], C1, bb[j]));
          e[g4 * 4 + j] = ev;
          lacc[j] += ev;
        }
      }
      // pack P -> PV A-frags
      unsigned p0 = pk2(e[0], e[1]),  p1 = pk2(e[2], e[3]);
      unsigned p2 = pk2(e[4], e[5]),  p3 = pk2(e[6], e[7]);
      unsigned p4 = pk2(e[8], e[9]),  p5 = pk2(e[10], e[11]);
      unsigned p6 = pk2(e[12], e[13]), p7 = pk2(e[14], e[15]);
      swap32(p0, p2); swap32(p1, p3);   // keys +0..15 of group
      swap32(p4, p6); swap32(p5, p7);   // keys +16..31 of group
      u32x4 u0 = {p0, p1, p2, p3}, u1 = {p4, p5, p6, p7};
      bf16x8 pa0 = __builtin_bit_cast(bf16x8, u0);
      bf16x8 pa1 = __builtin_bit_cast(bf16x8, u1);
      // PV: V rows d = l32 (o0) and 32+l32 (o1); key bytes 64g + 16hi (+32)
      const int r0 = l32, r1 = 32 + l32;
      bf16x8 v00 = *reinterpret_cast<const bf16x8*>(vt + r0 * 128 + swz(r0, 64 * g + 16 * hi));
      bf16x8 v01 = *reinterpret_cast<const bf16x8*>(vt + r0 * 128 + swz(r0, 64 * g + 16 * hi + 32));
      bf16x8 v10 = *reinterpret_cast<const bf16x8*>(vt + r1 * 128 + swz(r1, 64 * g + 16 * hi));
      bf16x8 v11 = *reinterpret_cast<const bf16x8*>(vt + r1 * 128 + swz(r1, 64 * g + 16 * hi + 32));
      o0 = mfma32(pa0, v00, o0);
      o0 = mfma32(pa1, v01, o0);
      o1 = mfma32(pa0, v10, o1);
      o1 = mfma32(pa1, v11, o1);
    }

    __syncthreads();                       // all waves done reading buf[cur]
    if (t + 1 < NT) {
      char* kb_ = kv_lds[cur ^ 1][0]; char* vb_ = kv_lds[cur ^ 1][1];
      *reinterpret_cast<bf16x8*>(kb_ + kr0 * 128 + swz(kr0, ks0 * 16)) = kreg0;
      *reinterpret_cast<bf16x8*>(kb_ + kr1 * 128 + swz(kr1, ks1 * 16)) = kreg1;
      *reinterpret_cast<bf16x8*>(vb_ + kr0 * 128 + swz(kr0, ks0 * 16)) = vreg0;
      *reinterpret_cast<bf16x8*>(vb_ + kr1 * 128 + swz(kr1, ks1 * 16)) = vreg1;
      __syncthreads();                     // buf[cur^1] ready for next tile
    }
  }

  // ---- epilogue: l-broadcast via LDS, normalize, write --------------------
  float ls = lacc[0] + lacc[1] + lacc[2] + lacc[3];
  ls += __shfl_xor(ls, 32, 64);
  if (hi == 0) lsum_lds[wv][l32] = ls;
  __syncthreads();
  f32x4 linv[4];
#pragma unroll
  for (int g = 0; g < 4; ++g) {
    f32x4 t = *reinterpret_cast<const f32x4*>(&lsum_lds[wv][8 * g + 4 * hi]);
#pragma unroll
    for (int j = 0; j < 4; ++j) linv[g][j] = 1.0f / t[j];
  }
  bf16* aop = AO + ((size_t)b * SEQ + qb) * DIMV + h * HDIM + l32;
#pragma unroll
  for (int r = 0; r < 16; ++r) {
    const int q = (r & 3) + 8 * (r >> 2) + 4 * hi;
    const float inv = linv[r >> 2][r & 3];
    aop[(size_t)q * DIMV]      = (bf16)(o0[r] * inv);
    aop[(size_t)q * DIMV + 32] = (bf16)(o1[r] * inv);
  }
}

// ---------------------------------------------------------------------------
// Kernel 3: y = AO @ Wproj + bproj + x  -> d_out (fp32)
// ---------------------------------------------------------------------------
__global__ __launch_bounds__(256) void gemm2_proj(
    const bf16* __restrict__ AO, const bf16* __restrict__ WT,
    const float* __restrict__ bproj, const float* __restrict__ x,
    float* __restrict__ Y) {
  const int tid = threadIdx.x;
  const int wave = tid >> 6, lane = tid & 63;
  const int l16 = lane & 15, lg = lane >> 4;
  const int Mbase = blockIdx.x * 128 + (wave >> 1) * 64;
  const int Nbase = blockIdx.y * 128 + (wave & 1) * 64;

  f32x4 acc[4][4] = {};
  for (int k0 = 0; k0 < DIMV; k0 += 32) {
    const int kb = k0 + lg * 8;
    bf16x8 af[4], bfr[4];
#pragma unroll
    for (int r = 0; r < 4; ++r) {
      af[r] = *reinterpret_cast<const bf16x8*>(
          AO + (size_t)(Mbase + r * 16 + l16) * DIMV + kb);
      bfr[r] = *reinterpret_cast<const bf16x8*>(
          WT + (size_t)(Nbase + r * 16 + l16) * DIMV + kb);
    }
#pragma unroll
    for (int mr = 0; mr < 4; ++mr)
#pragma unroll
      for (int nr = 0; nr < 4; ++nr)
        acc[mr][nr] = mfma16(af[mr], bfr[nr], acc[mr][nr]);
  }
#pragma unroll
  for (int mr = 0; mr < 4; ++mr)
#pragma unroll
    for (int nr = 0; nr < 4; ++nr)
#pragma unroll
      for (int j = 0; j < 4; ++j) {
        const int n = Nbase + nr * 16 + l16;
        const int m = Mbase + mr * 16 + lg * 4 + j;
        Y[(size_t)m * DIMV + n] = acc[mr][nr][j] + bproj[n] + x[(size_t)m * DIMV + n];
      }
}

// ---------------------------------------------------------------------------
// Kernel 4: in-place LayerNorm over rows of 512
// ---------------------------------------------------------------------------
__global__ __launch_bounds__(128) void ln_kernel(float* __restrict__ Y,
                                                 const float* __restrict__ gamma,
                                                 const float* __restrict__ beta) {
  const int row = blockIdx.x, tid = threadIdx.x;
  float* rp = Y + (size_t)row * DIMV;
  f32x4 v = *reinterpret_cast<const f32x4*>(rp + tid * 4);
  float s = v[0] + v[1] + v[2] + v[3];
  float q = v[0] * v[0] + v[1] * v[1] + v[2] * v[2] + v[3] * v[3];
#pragma unroll
  for (int off = 1; off < 64; off <<= 1) {
    s += __shfl_xor(s, off, 64);
    q += __shfl_xor(q, off, 64);
  }
  __shared__ float sh[4];
  if ((tid & 63) == 0) { sh[(tid >> 6) * 2] = s; sh[(tid >> 6) * 2 + 1] = q; }
  __syncthreads();
  const float ts = sh[0] + sh[2], tq = sh[1] + sh[3];
  const float mu = ts * (1.0f / DIMV);
  const float var = tq * (1.0f / DIMV) - mu * mu;
  const float rs = rsqrtf(var + 1e-5f);
  f32x4 ov;
#pragma unroll
  for (int i = 0; i < 4; ++i) {
    const int c = tid * 4 + i;
    ov[i] = (v[i] - mu) * rs * gamma[c] + beta[c];
  }
  *reinterpret_cast<f32x4*>(rp + tid * 4) = ov;
}

// ---------------------------------------------------------------------------
extern "C" void kernel_launch(void* const* d_in, const int* in_sizes, int n_in,
                              void* d_out, int out_size, void* d_ws, size_t ws_size,
                              hipStream_t stream) {
  const float* x      = (const float*)d_in[0];
  const int*   pmask  = (const int*)d_in[1];
  const float* Wqkv   = (const float*)d_in[2];
  const float* bqkv   = (const float*)d_in[3];
  const float* Wproj  = (const float*)d_in[4];
  const float* bproj  = (const float*)d_in[5];
  const float* gamma  = (const float*)d_in[6];
  const float* beta   = (const float*)d_in[7];
  const float* cosT   = (const float*)d_in[8];
  const float* sinT   = (const float*)d_in[9];
  float* out = (float*)d_out;

  char* ws = (char*)d_ws;
  const size_t MB = 1048576;
  bf16* WqkvT  = (bf16*)(ws);                       // 1.5 MiB
  bf16* WprojT = (bf16*)(ws + 3 * MB / 2);          // 0.5 MiB
  bf16* Q      = (bf16*)(ws + 2 * MB);              // 8 MiB
  bf16* Kd     = (bf16*)(ws + 10 * MB);             // 8 MiB
  bf16* VT     = (bf16*)(ws + 18 * MB);             // 8 MiB
  bf16* AO     = (bf16*)(ws + 26 * MB);             // 8 MiB (aliased with xb)
  bf16* xb     = AO;                                // xb dead before AO written
  float* BBias = (float*)(ws + 34 * MB);            // 32 KiB

  prep_w<<<2048, 256, 0, stream>>>(Wqkv, Wproj, x, pmask, WqkvT, WprojT, xb, BBias);
  gemm1_qkv_rope<<<dim3(M_TOT / 128, NQKV / 128), 256, 0, stream>>>(
      xb, WqkvT, bqkv, cosT, sinT, Q, Kd, VT);
  attn_kernel<<<dim3(SEQ / 128, BB_ * NH), 256, 0, stream>>>(Q, Kd, VT, BBias, AO);
  gemm2_proj<<<dim3(M_TOT / 128, DIMV / 128), 256, 0, stream>>>(AO, WprojT, bproj, x, out);
  ln_kernel<<<M_TOT, 128, 0, stream>>>(out, gamma, beta);
}

// Round 11
// 269.732 us; speedup vs baseline: 2.0367x; 1.1106x over previous
//
#include <hip/hip_runtime.h>
#include <hip/hip_bf16.h>

typedef __bf16 bf16;
typedef __attribute__((ext_vector_type(8))) __bf16 bf16x8;
typedef __attribute__((ext_vector_type(2))) __bf16 bf16x2;
typedef __attribute__((ext_vector_type(4))) float f32x4;
typedef __attribute__((ext_vector_type(16))) float f32x16;
typedef __attribute__((ext_vector_type(4))) unsigned int u32x4;

#define DIMV 512
#define NH 8
#define HDIM 64
#define SEQ 4096
#define BB_ 2
#define M_TOT (BB_ * SEQ)   /* 8192 */
#define NQKV 1536
#define KVBLK 64            /* keys per LDS tile */

static __device__ __forceinline__ f32x4 mfma16(bf16x8 a, bf16x8 b, f32x4 c) {
  return __builtin_amdgcn_mfma_f32_16x16x32_bf16(a, b, c, 0, 0, 0);
}
static __device__ __forceinline__ f32x16 mfma32(bf16x8 a, bf16x8 b, f32x16 c) {
  return __builtin_amdgcn_mfma_f32_32x32x16_bf16(a, b, c, 0, 0, 0);
}
static __device__ __forceinline__ unsigned pk2(float a, float b) {
  bf16x2 t; t[0] = (bf16)a; t[1] = (bf16)b;
  return __builtin_bit_cast(unsigned, t);
}
// v_permlane32_swap_b32: a[hi lanes] <-> b[lo lanes] (CDNA4)
static __device__ __forceinline__ void swap32(unsigned& a, unsigned& b) {
  asm("v_permlane32_swap_b32 %0, %1" : "+v"(a), "+v"(b));
}
// XOR swizzle within a 128-B LDS row: spreads column-slices across banks
static __device__ __forceinline__ int swz(int row, int byteoff) {
  return byteoff ^ ((row & 7) << 4);
}

// ---------------------------------------------------------------------------
// Kernel 0: weight transpose->bf16, x->bf16, mask->bias floats
// ---------------------------------------------------------------------------
__global__ void prep_w(const float* __restrict__ Wqkv, const float* __restrict__ Wproj,
                       const float* __restrict__ x, const int* __restrict__ mask,
                       bf16* __restrict__ WqkvT, bf16* __restrict__ WprojT,
                       bf16* __restrict__ xb, float* __restrict__ BBias) {
  const int t1 = DIMV * NQKV;            // WqkvT
  const int t2 = t1 + DIMV * DIMV;       // WprojT
  const int t3 = t2 + M_TOT * DIMV;      // xb
  const int t4 = t3 + BB_ * SEQ;         // bias
  for (int i = blockIdx.x * blockDim.x + threadIdx.x; i < t4;
       i += gridDim.x * blockDim.x) {
    if (i < t1) {
      int n = i / DIMV, k = i - n * DIMV;
      WqkvT[i] = (bf16)Wqkv[(size_t)k * NQKV + n];
    } else if (i < t2) {
      int o = i - t1;
      int n = o / DIMV, k = o - n * DIMV;
      WprojT[o] = (bf16)Wproj[(size_t)k * DIMV + n];
    } else if (i < t3) {
      int o = i - t2;
      xb[o] = (bf16)x[o];
    } else {
      int o = i - t3;
      BBias[o] = mask[o] ? -1.0e30f : 0.0f;
    }
  }
}

// ---------------------------------------------------------------------------
// Kernel 1: QKV = x @ Wqkv + b, fused RoPE, scatter to Q,K [bh][l][d], VT [bh][d][l]
// V-blocks (blockIdx.y in {8..11}) use SWAPPED mfma operands so the C/D
// layout transposes: col = seq pos l -> V^T stores become 32-B contiguous
// segments instead of 2-B stores at 8-KB lane stride.
// ---------------------------------------------------------------------------
__global__ __launch_bounds__(256) void gemm1_qkv_rope(
    const bf16* __restrict__ xb, const bf16* __restrict__ WT,
    const float* __restrict__ bqkv, const float* __restrict__ cosT,
    const float* __restrict__ sinT, bf16* __restrict__ Q,
    bf16* __restrict__ Kd, bf16* __restrict__ VT) {
  const int tid = threadIdx.x;
  const int wave = tid >> 6, lane = tid & 63;
  const int l16 = lane & 15, lg = lane >> 4;
  const int Mbase = blockIdx.x * 128 + (wave >> 1) * 64;
  const int Nbase = blockIdx.y * 128 + (wave & 1) * 64;
  const int gblk = (blockIdx.y * 128) >> 9;   // 0=Q, 1=K, 2=V (block-uniform)

  f32x4 acc[4][4] = {};
  if (gblk != 2) {
    for (int k0 = 0; k0 < DIMV; k0 += 32) {
      const int kb = k0 + lg * 8;
      bf16x8 af[4], bfr[4];
#pragma unroll
      for (int r = 0; r < 4; ++r) {
        af[r] = *reinterpret_cast<const bf16x8*>(
            xb + (size_t)(Mbase + r * 16 + l16) * DIMV + kb);
        bfr[r] = *reinterpret_cast<const bf16x8*>(
            WT + (size_t)(Nbase + r * 16 + l16) * DIMV + kb);
      }
#pragma unroll
      for (int mr = 0; mr < 4; ++mr)
#pragma unroll
        for (int nr = 0; nr < 4; ++nr)
          acc[mr][nr] = mfma16(af[mr], bfr[nr], acc[mr][nr]);
    }
    // Epilogue (Q/K): D[row=l, col=n].  n = Nbase+nr*16+l16, l = Mbase+mr*16+lg*4+j
#pragma unroll
    for (int mr = 0; mr < 4; ++mr) {
#pragma unroll
      for (int nr = 0; nr < 4; ++nr) {
#pragma unroll
        for (int j = 0; j < 4; ++j) {
          const int n = Nbase + nr * 16 + l16;
          const int m = Mbase + mr * 16 + lg * 4 + j;
          const int rem = n & 511, h = rem >> 6, d = rem & 63;
          const int b = m >> 12, l = m & 4095;
          float val = acc[mr][nr][j] + bqkv[n];
          float pairval = acc[mr][nr ^ 2][j] + bqkv[n ^ 32];
          float c = cosT[l * HDIM + d], s = sinT[l * HDIM + d];
          float o = (d < 32) ? (val * c - pairval * s) : (val * c + pairval * s);
          bf16* dst = (gblk == 0) ? Q : Kd;
          dst[((size_t)(b * NH + h) * SEQ + l) * HDIM + d] = (bf16)o;
        }
      }
    }
  } else {
    // V path: swapped operands -> D[row=n, col=l]
    for (int k0 = 0; k0 < DIMV; k0 += 32) {
      const int kb = k0 + lg * 8;
      bf16x8 af[4], bfr[4];
#pragma unroll
      for (int r = 0; r < 4; ++r) {
        af[r] = *reinterpret_cast<const bf16x8*>(
            xb + (size_t)(Mbase + r * 16 + l16) * DIMV + kb);
        bfr[r] = *reinterpret_cast<const bf16x8*>(
            WT + (size_t)(Nbase + r * 16 + l16) * DIMV + kb);
      }
#pragma unroll
      for (int mr = 0; mr < 4; ++mr)
#pragma unroll
        for (int nr = 0; nr < 4; ++nr)
          acc[mr][nr] = mfma16(bfr[nr], af[mr], acc[mr][nr]);
    }
    // Epilogue (V): n = Nbase+nr*16+lg*4+j (row), l = Mbase+mr*16+l16 (col).
    // VT[(bh*64+d)*SEQ + l]: 16 consecutive lanes -> 16 consecutive l = 32 B.
#pragma unroll
    for (int mr = 0; mr < 4; ++mr) {
#pragma unroll
      for (int nr = 0; nr < 4; ++nr) {
#pragma unroll
        for (int j = 0; j < 4; ++j) {
          const int n = Nbase + nr * 16 + lg * 4 + j;
          const int m = Mbase + mr * 16 + l16;
          const int rem = n & 511, h = rem >> 6, d = rem & 63;
          const int b = m >> 12, l = m & 4095;
          float val = acc[mr][nr][j] + bqkv[n];
          VT[((size_t)(b * NH + h) * HDIM + d) * SEQ + l] = (bf16)val;
        }
      }
    }
  }
}

// ---------------------------------------------------------------------------
// Kernel 2: flash attention, swapped-QK^T 32x32, no max tracking.
// Grid (SEQ/128, B*H), 4 waves x 32-q tiles.  K/V staged per 64-key tile
// through XOR-swizzled, double-buffered LDS with coalesced global loads
// (issue-early / write-late).
// ---------------------------------------------------------------------------
__global__ __launch_bounds__(256) void attn_kernel(
    const bf16* __restrict__ Q, const bf16* __restrict__ Kd,
    const bf16* __restrict__ VT, const float* __restrict__ BBias,
    bf16* __restrict__ AO) {
  // [buf][K=0/V=1][64 rows][128 B]  = 32 KiB
  __shared__ __align__(16) char kv_lds[2][2][KVBLK * 128];
  __shared__ __align__(16) float lsum_lds[4][32];

  const int tid = threadIdx.x;
  const int wv = tid >> 6, lane = tid & 63;
  const int l32 = lane & 31, hi = lane >> 5;
  const int bh = blockIdx.y, b = bh >> 3, h = bh & 7;
  const int qb = blockIdx.x * 128 + wv * 32;
  const float C1 = 0.125f * 1.44269504f;  // 1/sqrt(64) * log2(e)

  // Q B-frags: qfrag[w] holds Q[qb + l32][16w + 8hi + j]
  const bf16* qrow = Q + ((size_t)bh * SEQ + qb + l32) * HDIM + 8 * hi;
  bf16x8 qfrag[4];
#pragma unroll
  for (int w = 0; w < 4; ++w)
    qfrag[w] = *reinterpret_cast<const bf16x8*>(qrow + 16 * w);

  // staging geometry: chunk c in [0,512): row = c>>3, slot = c&7 (16 B each)
  const bf16* Kbase = Kd + (size_t)bh * SEQ * HDIM;   // K[key][d] row = 128 B
  const bf16* Vbase = VT + (size_t)bh * HDIM * SEQ;   // V[d][key]
  const int c0 = tid, c1 = tid + 256;
  const int kr0 = c0 >> 3, ks0 = c0 & 7;
  const int kr1 = c1 >> 3, ks1 = c1 & 7;

  const float* bbp = BBias + b * SEQ + 4 * hi;

  f32x16 o0 = {}, o1 = {};
  f32x4 lacc = {};

  bf16x8 kreg0, kreg1, vreg0, vreg1;
  // ---- prologue: stage tile 0 --------------------------------------------
  {
    kreg0 = *reinterpret_cast<const bf16x8*>(Kbase + (size_t)kr0 * HDIM + ks0 * 8);
    kreg1 = *reinterpret_cast<const bf16x8*>(Kbase + (size_t)kr1 * HDIM + ks1 * 8);
    vreg0 = *reinterpret_cast<const bf16x8*>(Vbase + (size_t)kr0 * SEQ + ks0 * 8);
    vreg1 = *reinterpret_cast<const bf16x8*>(Vbase + (size_t)kr1 * SEQ + ks1 * 8);
    char* kb_ = kv_lds[0][0]; char* vb_ = kv_lds[0][1];
    *reinterpret_cast<bf16x8*>(kb_ + kr0 * 128 + swz(kr0, ks0 * 16)) = kreg0;
    *reinterpret_cast<bf16x8*>(kb_ + kr1 * 128 + swz(kr1, ks1 * 16)) = kreg1;
    *reinterpret_cast<bf16x8*>(vb_ + kr0 * 128 + swz(kr0, ks0 * 16)) = vreg0;
    *reinterpret_cast<bf16x8*>(vb_ + kr1 * 128 + swz(kr1, ks1 * 16)) = vreg1;
  }
  __syncthreads();

  const int NT = SEQ / KVBLK;
  for (int t = 0; t < NT; ++t) {
    const int cur = t & 1;
    const int kb = t * KVBLK;
    // ---- issue next tile's global loads early (T14) -----------------------
    if (t + 1 < NT) {
      const int nkb = kb + KVBLK;
      kreg0 = *reinterpret_cast<const bf16x8*>(Kbase + (size_t)(nkb + kr0) * HDIM + ks0 * 8);
      kreg1 = *reinterpret_cast<const bf16x8*>(Kbase + (size_t)(nkb + kr1) * HDIM + ks1 * 8);
      vreg0 = *reinterpret_cast<const bf16x8*>(Vbase + (size_t)kr0 * SEQ + nkb + ks0 * 8);
      vreg1 = *reinterpret_cast<const bf16x8*>(Vbase + (size_t)kr1 * SEQ + nkb + ks1 * 8);
    }

    // ---- compute the two 32-key groups of this tile -----------------------
    const char* kt = kv_lds[cur][0];
    const char* vt = kv_lds[cur][1];
#pragma unroll
    for (int g = 0; g < 2; ++g) {
      // S^T = K·Q^T over 32 keys
      f32x16 S = {};
#pragma unroll
      for (int w = 0; w < 4; ++w) {
        const int row = 32 * g + l32;
        bf16x8 kf = *reinterpret_cast<const bf16x8*>(
            kt + row * 128 + swz(row, 32 * w + 16 * hi));
        S = mfma32(kf, qfrag[w], S);
      }
      // e = exp2(s*C1 + bias[key]); key = kb + 32g + 8*(r>>2) + 4hi + (r&3)
      float e[16];
#pragma unroll
      for (int g4 = 0; g4 < 4; ++g4) {
        f32x4 bb = *reinterpret_cast<const f32x4*>(bbp + kb + 32 * g + 8 * g4);
#pragma unroll
        for (int j = 0; j < 4; ++j) {
          float ev = __builtin_amdgcn_exp2f(fmaf(S[g4 * 4 + j], C1, bb[j]));
          e[g4 * 4 + j] = ev;
          lacc[j] += ev;
        }
      }
      // pack P -> PV A-frags
      unsigned p0 = pk2(e[0], e[1]),  p1 = pk2(e[2], e[3]);
      unsigned p2 = pk2(e[4], e[5]),  p3 = pk2(e[6], e[7]);
      unsigned p4 = pk2(e[8], e[9]),  p5 = pk2(e[10], e[11]);
      unsigned p6 = pk2(e[12], e[13]), p7 = pk2(e[14], e[15]);
      swap32(p0, p2); swap32(p1, p3);   // keys +0..15 of group
      swap32(p4, p6); swap32(p5, p7);   // keys +16..31 of group
      u32x4 u0 = {p0, p1, p2, p3}, u1 = {p4, p5, p6, p7};
      bf16x8 pa0 = __builtin_bit_cast(bf16x8, u0);
      bf16x8 pa1 = __builtin_bit_cast(bf16x8, u1);
      // PV: V rows d = l32 (o0) and 32+l32 (o1); key bytes 64g + 16hi (+32)
      const int r0 = l32, r1 = 32 + l32;
      bf16x8 v00 = *reinterpret_cast<const bf16x8*>(vt + r0 * 128 + swz(r0, 64 * g + 16 * hi));
      bf16x8 v01 = *reinterpret_cast<const bf16x8*>(vt + r0 * 128 + swz(r0, 64 * g + 16 * hi + 32));
      bf16x8 v10 = *reinterpret_cast<const bf16x8*>(vt + r1 * 128 + swz(r1, 64 * g + 16 * hi));
      bf16x8 v11 = *reinterpret_cast<const bf16x8*>(vt + r1 * 128 + swz(r1, 64 * g + 16 * hi + 32));
      o0 = mfma32(pa0, v00, o0);
      o0 = mfma32(pa1, v01, o0);
      o1 = mfma32(pa0, v10, o1);
      o1 = mfma32(pa1, v11, o1);
    }

    __syncthreads();                       // all waves done reading buf[cur]
    if (t + 1 < NT) {
      char* kb_ = kv_lds[cur ^ 1][0]; char* vb_ = kv_lds[cur ^ 1][1];
      *reinterpret_cast<bf16x8*>(kb_ + kr0 * 128 + swz(kr0, ks0 * 16)) = kreg0;
      *reinterpret_cast<bf16x8*>(kb_ + kr1 * 128 + swz(kr1, ks1 * 16)) = kreg1;
      *reinterpret_cast<bf16x8*>(vb_ + kr0 * 128 + swz(kr0, ks0 * 16)) = vreg0;
      *reinterpret_cast<bf16x8*>(vb_ + kr1 * 128 + swz(kr1, ks1 * 16)) = vreg1;
      __syncthreads();                     // buf[cur^1] ready for next tile
    }
  }

  // ---- epilogue: l-broadcast via LDS, normalize, write --------------------
  float ls = lacc[0] + lacc[1] + lacc[2] + lacc[3];
  ls += __shfl_xor(ls, 32, 64);
  if (hi == 0) lsum_lds[wv][l32] = ls;
  __syncthreads();
  f32x4 linv[4];
#pragma unroll
  for (int g = 0; g < 4; ++g) {
    f32x4 t = *reinterpret_cast<const f32x4*>(&lsum_lds[wv][8 * g + 4 * hi]);
#pragma unroll
    for (int j = 0; j < 4; ++j) linv[g][j] = 1.0f / t[j];
  }
  bf16* aop = AO + ((size_t)b * SEQ + qb) * DIMV + h * HDIM + l32;
#pragma unroll
  for (int r = 0; r < 16; ++r) {
    const int q = (r & 3) + 8 * (r >> 2) + 4 * hi;
    const float inv = linv[r >> 2][r & 3];
    aop[(size_t)q * DIMV]      = (bf16)(o0[r] * inv);
    aop[(size_t)q * DIMV + 32] = (bf16)(o1[r] * inv);
  }
}

// ---------------------------------------------------------------------------
// Kernel 3: y = AO @ Wproj + bproj + x  -> d_out (fp32)
// ---------------------------------------------------------------------------
__global__ __launch_bounds__(256) void gemm2_proj(
    const bf16* __restrict__ AO, const bf16* __restrict__ WT,
    const float* __restrict__ bproj, const float* __restrict__ x,
    float* __restrict__ Y) {
  const int tid = threadIdx.x;
  const int wave = tid >> 6, lane = tid & 63;
  const int l16 = lane & 15, lg = lane >> 4;
  const int Mbase = blockIdx.x * 128 + (wave >> 1) * 64;
  const int Nbase = blockIdx.y * 128 + (wave & 1) * 64;

  f32x4 acc[4][4] = {};
  for (int k0 = 0; k0 < DIMV; k0 += 32) {
    const int kb = k0 + lg * 8;
    bf16x8 af[4], bfr[4];
#pragma unroll
    for (int r = 0; r < 4; ++r) {
      af[r] = *reinterpret_cast<const bf16x8*>(
          AO + (size_t)(Mbase + r * 16 + l16) * DIMV + kb);
      bfr[r] = *reinterpret_cast<const bf16x8*>(
          WT + (size_t)(Nbase + r * 16 + l16) * DIMV + kb);
    }
#pragma unroll
    for (int mr = 0; mr < 4; ++mr)
#pragma unroll
      for (int nr = 0; nr < 4; ++nr)
        acc[mr][nr] = mfma16(af[mr], bfr[nr], acc[mr][nr]);
  }
#pragma unroll
  for (int mr = 0; mr < 4; ++mr)
#pragma unroll
    for (int nr = 0; nr < 4; ++nr)
#pragma unroll
      for (int j = 0; j < 4; ++j) {
        const int n = Nbase + nr * 16 + l16;
        const int m = Mbase + mr * 16 + lg * 4 + j;
        Y[(size_t)m * DIMV + n] = acc[mr][nr][j] + bproj[n] + x[(size_t)m * DIMV + n];
      }
}

// ---------------------------------------------------------------------------
// Kernel 4: in-place LayerNorm over rows of 512
// ---------------------------------------------------------------------------
__global__ __launch_bounds__(128) void ln_kernel(float* __restrict__ Y,
                                                 const float* __restrict__ gamma,
                                                 const float* __restrict__ beta) {
  const int row = blockIdx.x, tid = threadIdx.x;
  float* rp = Y + (size_t)row * DIMV;
  f32x4 v = *reinterpret_cast<const f32x4*>(rp + tid * 4);
  float s = v[0] + v[1] + v[2] + v[3];
  float q = v[0] * v[0] + v[1] * v[1] + v[2] * v[2] + v[3] * v[3];
#pragma unroll
  for (int off = 1; off < 64; off <<= 1) {
    s += __shfl_xor(s, off, 64);
    q += __shfl_xor(q, off, 64);
  }
  __shared__ float sh[4];
  if ((tid & 63) == 0) { sh[(tid >> 6) * 2] = s; sh[(tid >> 6) * 2 + 1] = q; }
  __syncthreads();
  const float ts = sh[0] + sh[2], tq = sh[1] + sh[3];
  const float mu = ts * (1.0f / DIMV);
  const float var = tq * (1.0f / DIMV) - mu * mu;
  const float rs = rsqrtf(var + 1e-5f);
  f32x4 ov;
#pragma unroll
  for (int i = 0; i < 4; ++i) {
    const int c = tid * 4 + i;
    ov[i] = (v[i] - mu) * rs * gamma[c] + beta[c];
  }
  *reinterpret_cast<f32x4*>(rp + tid * 4) = ov;
}

// ---------------------------------------------------------------------------
extern "C" void kernel_launch(void* const* d_in, const int* in_sizes, int n_in,
                              void* d_out, int out_size, void* d_ws, size_t ws_size,
                              hipStream_t stream) {
  const float* x      = (const float*)d_in[0];
  const int*   pmask  = (const int*)d_in[1];
  const float* Wqkv   = (const float*)d_in[2];
  const float* bqkv   = (const float*)d_in[3];
  const float* Wproj  = (const float*)d_in[4];
  const float* bproj  = (const float*)d_in[5];
  const float* gamma  = (const float*)d_in[6];
  const float* beta   = (const float*)d_in[7];
  const float* cosT   = (const float*)d_in[8];
  const float* sinT   = (const float*)d_in[9];
  float* out = (float*)d_out;

  char* ws = (char*)d_ws;
  const size_t MB = 1048576;
  bf16* WqkvT  = (bf16*)(ws);                       // 1.5 MiB
  bf16* WprojT = (bf16*)(ws + 3 * MB / 2);          // 0.5 MiB
  bf16* Q      = (bf16*)(ws + 2 * MB);              // 8 MiB
  bf16* Kd     = (bf16*)(ws + 10 * MB);             // 8 MiB
  bf16* VT     = (bf16*)(ws + 18 * MB);             // 8 MiB
  bf16* AO     = (bf16*)(ws + 26 * MB);             // 8 MiB (aliased with xb)
  bf16* xb     = AO;                                // xb dead before AO written
  float* BBias = (float*)(ws + 34 * MB);            // 32 KiB

  prep_w<<<2048, 256, 0, stream>>>(Wqkv, Wproj, x, pmask, WqkvT, WprojT, xb, BBias);
  gemm1_qkv_rope<<<dim3(M_TOT / 128, NQKV / 128), 256, 0, stream>>>(
      xb, WqkvT, bqkv, cosT, sinT, Q, Kd, VT);
  attn_kernel<<<dim3(SEQ / 128, BB_ * NH), 256, 0, stream>>>(Q, Kd, VT, BBias, AO);
  gemm2_proj<<<dim3(M_TOT / 128, DIMV / 128), 256, 0, stream>>>(AO, WprojT, bproj, x, out);
  ln_kernel<<<M_TOT, 128, 0, stream>>>(out, gamma, beta);
}

// Round 14
// 255.178 us; speedup vs baseline: 2.1528x; 1.0570x over previous
//
#include <hip/hip_runtime.h>
#include <hip/hip_bf16.h>

typedef __bf16 bf16;
typedef __attribute__((ext_vector_type(8))) __bf16 bf16x8;
typedef __attribute__((ext_vector_type(2))) __bf16 bf16x2;
typedef __attribute__((ext_vector_type(4))) float f32x4;
typedef __attribute__((ext_vector_type(16))) float f32x16;
typedef __attribute__((ext_vector_type(4))) unsigned int u32x4;

#define DIMV 512
#define NH 8
#define HDIM 64
#define SEQ 4096
#define BB_ 2
#define M_TOT (BB_ * SEQ)   /* 8192 */
#define NQKV 1536
#define KVBLK 64            /* keys per LDS tile */

static __device__ __forceinline__ f32x4 mfma16(bf16x8 a, bf16x8 b, f32x4 c) {
  return __builtin_amdgcn_mfma_f32_16x16x32_bf16(a, b, c, 0, 0, 0);
}
static __device__ __forceinline__ f32x16 mfma32(bf16x8 a, bf16x8 b, f32x16 c) {
  return __builtin_amdgcn_mfma_f32_32x32x16_bf16(a, b, c, 0, 0, 0);
}
static __device__ __forceinline__ unsigned pk2(float a, float b) {
  bf16x2 t; t[0] = (bf16)a; t[1] = (bf16)b;
  return __builtin_bit_cast(unsigned, t);
}
// v_permlane32_swap_b32: a[hi lanes] <-> b[lo lanes] (CDNA4)
static __device__ __forceinline__ void swap32(unsigned& a, unsigned& b) {
  asm("v_permlane32_swap_b32 %0, %1" : "+v"(a), "+v"(b));
}
// XOR swizzle within a 128-B LDS row: spreads column-slices across banks
static __device__ __forceinline__ int swz(int row, int byteoff) {
  return byteoff ^ ((row & 7) << 4);
}
// async global->LDS, 16 B per lane; LDS dest = uniform base + lane*16
static __device__ __forceinline__ void gload_lds16(const bf16* g, bf16* lds) {
  __builtin_amdgcn_global_load_lds(
      (const __attribute__((address_space(1))) unsigned int*)g,
      (__attribute__((address_space(3))) unsigned int*)lds, 16, 0, 0);
}

// ---------------------------------------------------------------------------
// Kernel 0: weight transpose->bf16, x->bf16, mask->bias floats
// ---------------------------------------------------------------------------
__global__ void prep_w(const float* __restrict__ Wqkv, const float* __restrict__ Wproj,
                       const float* __restrict__ x, const int* __restrict__ mask,
                       bf16* __restrict__ WqkvT, bf16* __restrict__ WprojT,
                       bf16* __restrict__ xb, float* __restrict__ BBias) {
  const int t1 = DIMV * NQKV;            // WqkvT
  const int t2 = t1 + DIMV * DIMV;       // WprojT
  const int t3 = t2 + M_TOT * DIMV;      // xb
  const int t4 = t3 + BB_ * SEQ;         // bias
  for (int i = blockIdx.x * blockDim.x + threadIdx.x; i < t4;
       i += gridDim.x * blockDim.x) {
    if (i < t1) {
      int n = i / DIMV, k = i - n * DIMV;
      WqkvT[i] = (bf16)Wqkv[(size_t)k * NQKV + n];
    } else if (i < t2) {
      int o = i - t1;
      int n = o / DIMV, k = o - n * DIMV;
      WprojT[o] = (bf16)Wproj[(size_t)k * DIMV + n];
    } else if (i < t3) {
      int o = i - t2;
      xb[o] = (bf16)x[o];
    } else {
      int o = i - t3;
      BBias[o] = mask[o] ? -1.0e30f : 0.0f;
    }
  }
}

// ---------------------------------------------------------------------------
// Kernel 1: QKV = x @ Wqkv + b, fused RoPE, scatter.  m97-style LDS staging:
// per 32-K step, A(128x32) + B(128x32) staged via global_load_lds width=16
// (4 instr/thread), linear LDS, ds_read_b128 frags.  V-blocks use swapped
// mfma operands -> transposed C/D -> contiguous V^T stores.
// ---------------------------------------------------------------------------
__global__ __launch_bounds__(256) void gemm1_qkv_rope(
    const bf16* __restrict__ xb, const bf16* __restrict__ WT,
    const float* __restrict__ bqkv, const float* __restrict__ cosT,
    const float* __restrict__ sinT, bf16* __restrict__ Q,
    bf16* __restrict__ Kd, bf16* __restrict__ VT) {
  __shared__ __align__(16) bf16 As[128 * 32];
  __shared__ __align__(16) bf16 Bs[128 * 32];
  const int tid = threadIdx.x;
  const int wave = tid >> 6, lane = tid & 63;
  const int l16 = lane & 15, lg = lane >> 4;
  const int Mblk = blockIdx.x * 128, Nblk = blockIdx.y * 128;
  const int Mbase = Mblk + (wave >> 1) * 64;
  const int Nbase = Nblk + (wave & 1) * 64;
  const int gblk = (blockIdx.y * 128) >> 9;   // 0=Q, 1=K, 2=V (block-uniform)

  // staging: wave w stages rows [w*32, w*32+32) of each tile; 2 instr each.
  // instr j: lane l -> row w*32 + j*16 + (l>>2), k-slot (l&3)*8
  const bf16* Ag = xb + (size_t)(Mblk + wave * 32 + (lane >> 2)) * DIMV + (lane & 3) * 8;
  const bf16* Bg = WT + (size_t)(Nblk + wave * 32 + (lane >> 2)) * DIMV + (lane & 3) * 8;
  bf16* AsW = As + wave * 32 * 32;
  bf16* BsW = Bs + wave * 32 * 32;

  f32x4 acc[4][4] = {};
  for (int k0 = 0; k0 < DIMV; k0 += 32) {
    gload_lds16(Ag + k0, AsW);
    gload_lds16(Ag + k0 + (size_t)16 * DIMV, AsW + 16 * 32);
    gload_lds16(Bg + k0, BsW);
    gload_lds16(Bg + k0 + (size_t)16 * DIMV, BsW + 16 * 32);
    __syncthreads();                        // drains vmcnt: tiles resident

    bf16x8 af[4], bfr[4];
#pragma unroll
    for (int r = 0; r < 4; ++r) {
      af[r] = *reinterpret_cast<const bf16x8*>(
          As + ((wave >> 1) * 64 + r * 16 + l16) * 32 + lg * 8);
      bfr[r] = *reinterpret_cast<const bf16x8*>(
          Bs + ((wave & 1) * 64 + r * 16 + l16) * 32 + lg * 8);
    }
    if (gblk != 2) {
#pragma unroll
      for (int mr = 0; mr < 4; ++mr)
#pragma unroll
        for (int nr = 0; nr < 4; ++nr)
          acc[mr][nr] = mfma16(af[mr], bfr[nr], acc[mr][nr]);
    } else {
#pragma unroll
      for (int mr = 0; mr < 4; ++mr)
#pragma unroll
        for (int nr = 0; nr < 4; ++nr)
          acc[mr][nr] = mfma16(bfr[nr], af[mr], acc[mr][nr]);
    }
    __syncthreads();                        // LDS free for next stage
  }

  if (gblk != 2) {
    // Epilogue (Q/K): D[row=l, col=n].  n = Nbase+nr*16+l16, l = Mbase+mr*16+lg*4+j
#pragma unroll
    for (int mr = 0; mr < 4; ++mr) {
#pragma unroll
      for (int nr = 0; nr < 4; ++nr) {
#pragma unroll
        for (int j = 0; j < 4; ++j) {
          const int n = Nbase + nr * 16 + l16;
          const int m = Mbase + mr * 16 + lg * 4 + j;
          const int rem = n & 511, h = rem >> 6, d = rem & 63;
          const int b = m >> 12, l = m & 4095;
          float val = acc[mr][nr][j] + bqkv[n];
          float pairval = acc[mr][nr ^ 2][j] + bqkv[n ^ 32];
          float c = cosT[l * HDIM + d], s = sinT[l * HDIM + d];
          float o = (d < 32) ? (val * c - pairval * s) : (val * c + pairval * s);
          bf16* dst = (gblk == 0) ? Q : Kd;
          dst[((size_t)(b * NH + h) * SEQ + l) * HDIM + d] = (bf16)o;
        }
      }
    }
  } else {
    // Epilogue (V): n = Nbase+nr*16+lg*4+j (row), l = Mbase+mr*16+l16 (col).
#pragma unroll
    for (int mr = 0; mr < 4; ++mr) {
#pragma unroll
      for (int nr = 0; nr < 4; ++nr) {
#pragma unroll
        for (int j = 0; j < 4; ++j) {
          const int n = Nbase + nr * 16 + lg * 4 + j;
          const int m = Mbase + mr * 16 + l16;
          const int rem = n & 511, h = rem >> 6, d = rem & 63;
          const int b = m >> 12, l = m & 4095;
          float val = acc[mr][nr][j] + bqkv[n];
          VT[((size_t)(b * NH + h) * HDIM + d) * SEQ + l] = (bf16)val;
        }
      }
    }
  }
}

// ---------------------------------------------------------------------------
// Kernel 2: flash attention, swapped-QK^T 32x32, no max tracking.
// Grid (SEQ/128, B*H), 4 waves x 32-q tiles.  K/V staged per 64-key tile
// through XOR-swizzled, double-buffered LDS.  ONE barrier per tile: tile t
// writes buf[(t+1)&1], whose prior readers (tile t-1) are ordered by the
// barrier at the end of t-1.
// ---------------------------------------------------------------------------
__global__ __launch_bounds__(256) void attn_kernel(
    const bf16* __restrict__ Q, const bf16* __restrict__ Kd,
    const bf16* __restrict__ VT, const float* __restrict__ BBias,
    bf16* __restrict__ AO) {
  // [buf][K=0/V=1][64 rows][128 B]  = 32 KiB
  __shared__ __align__(16) char kv_lds[2][2][KVBLK * 128];
  __shared__ __align__(16) float lsum_lds[4][32];

  const int tid = threadIdx.x;
  const int wv = tid >> 6, lane = tid & 63;
  const int l32 = lane & 31, hi = lane >> 5;
  const int bh = blockIdx.y, b = bh >> 3, h = bh & 7;
  const int qb = blockIdx.x * 128 + wv * 32;
  const float C1 = 0.125f * 1.44269504f;  // 1/sqrt(64) * log2(e)

  // Q B-frags: qfrag[w] holds Q[qb + l32][16w + 8hi + j]
  const bf16* qrow = Q + ((size_t)bh * SEQ + qb + l32) * HDIM + 8 * hi;
  bf16x8 qfrag[4];
#pragma unroll
  for (int w = 0; w < 4; ++w)
    qfrag[w] = *reinterpret_cast<const bf16x8*>(qrow + 16 * w);

  // staging geometry: chunk c in [0,512): row = c>>3, slot = c&7 (16 B each)
  const bf16* Kbase = Kd + (size_t)bh * SEQ * HDIM;   // K[key][d] row = 128 B
  const bf16* Vbase = VT + (size_t)bh * HDIM * SEQ;   // V[d][key]
  const int c0 = tid, c1 = tid + 256;
  const int kr0 = c0 >> 3, ks0 = c0 & 7;
  const int kr1 = c1 >> 3, ks1 = c1 & 7;

  const float* bbp = BBias + b * SEQ + 4 * hi;

  f32x16 o0 = {}, o1 = {};
  f32x4 lacc = {};

  bf16x8 kreg0, kreg1, vreg0, vreg1;
  // ---- prologue: stage tile 0 --------------------------------------------
  {
    kreg0 = *reinterpret_cast<const bf16x8*>(Kbase + (size_t)kr0 * HDIM + ks0 * 8);
    kreg1 = *reinterpret_cast<const bf16x8*>(Kbase + (size_t)kr1 * HDIM + ks1 * 8);
    vreg0 = *reinterpret_cast<const bf16x8*>(Vbase + (size_t)kr0 * SEQ + ks0 * 8);
    vreg1 = *reinterpret_cast<const bf16x8*>(Vbase + (size_t)kr1 * SEQ + ks1 * 8);
    char* kb_ = kv_lds[0][0]; char* vb_ = kv_lds[0][1];
    *reinterpret_cast<bf16x8*>(kb_ + kr0 * 128 + swz(kr0, ks0 * 16)) = kreg0;
    *reinterpret_cast<bf16x8*>(kb_ + kr1 * 128 + swz(kr1, ks1 * 16)) = kreg1;
    *reinterpret_cast<bf16x8*>(vb_ + kr0 * 128 + swz(kr0, ks0 * 16)) = vreg0;
    *reinterpret_cast<bf16x8*>(vb_ + kr1 * 128 + swz(kr1, ks1 * 16)) = vreg1;
  }
  __syncthreads();

  const int NT = SEQ / KVBLK;
  for (int t = 0; t < NT; ++t) {
    const int cur = t & 1;
    const int kb = t * KVBLK;
    // ---- issue next tile's global loads early (T14) -----------------------
    if (t + 1 < NT) {
      const int nkb = kb + KVBLK;
      kreg0 = *reinterpret_cast<const bf16x8*>(Kbase + (size_t)(nkb + kr0) * HDIM + ks0 * 8);
      kreg1 = *reinterpret_cast<const bf16x8*>(Kbase + (size_t)(nkb + kr1) * HDIM + ks1 * 8);
      vreg0 = *reinterpret_cast<const bf16x8*>(Vbase + (size_t)kr0 * SEQ + nkb + ks0 * 8);
      vreg1 = *reinterpret_cast<const bf16x8*>(Vbase + (size_t)kr1 * SEQ + nkb + ks1 * 8);
    }

    // ---- compute the two 32-key groups of this tile -----------------------
    const char* kt = kv_lds[cur][0];
    const char* vt = kv_lds[cur][1];
#pragma unroll
    for (int g = 0; g < 2; ++g) {
      // S^T = K·Q^T over 32 keys
      f32x16 S = {};
#pragma unroll
      for (int w = 0; w < 4; ++w) {
        const int row = 32 * g + l32;
        bf16x8 kf = *reinterpret_cast<const bf16x8*>(
            kt + row * 128 + swz(row, 32 * w + 16 * hi));
        S = mfma32(kf, qfrag[w], S);
      }
      // e = exp2(s*C1 + bias[key]); key = kb + 32g + 8*(r>>2) + 4hi + (r&3)
      float e[16];
#pragma unroll
      for (int g4 = 0; g4 < 4; ++g4) {
        f32x4 bb = *reinterpret_cast<const f32x4*>(bbp + kb + 32 * g + 8 * g4);
#pragma unroll
        for (int j = 0; j < 4; ++j) {
          float ev = __builtin_amdgcn_exp2f(fmaf(S[g4 * 4 + j], C1, bb[j]));
          e[g4 * 4 + j] = ev;
          lacc[j] += ev;
        }
      }
      // pack P -> PV A-frags
      unsigned p0 = pk2(e[0], e[1]),  p1 = pk2(e[2], e[3]);
      unsigned p2 = pk2(e[4], e[5]),  p3 = pk2(e[6], e[7]);
      unsigned p4 = pk2(e[8], e[9]),  p5 = pk2(e[10], e[11]);
      unsigned p6 = pk2(e[12], e[13]), p7 = pk2(e[14], e[15]);
      swap32(p0, p2); swap32(p1, p3);   // keys +0..15 of group
      swap32(p4, p6); swap32(p5, p7);   // keys +16..31 of group
      u32x4 u0 = {p0, p1, p2, p3}, u1 = {p4, p5, p6, p7};
      bf16x8 pa0 = __builtin_bit_cast(bf16x8, u0);
      bf16x8 pa1 = __builtin_bit_cast(bf16x8, u1);
      // PV: V rows d = l32 (o0) and 32+l32 (o1); key bytes 64g + 16hi (+32)
      const int r0 = l32, r1 = 32 + l32;
      bf16x8 v00 = *reinterpret_cast<const bf16x8*>(vt + r0 * 128 + swz(r0, 64 * g + 16 * hi));
      bf16x8 v01 = *reinterpret_cast<const bf16x8*>(vt + r0 * 128 + swz(r0, 64 * g + 16 * hi + 32));
      bf16x8 v10 = *reinterpret_cast<const bf16x8*>(vt + r1 * 128 + swz(r1, 64 * g + 16 * hi));
      bf16x8 v11 = *reinterpret_cast<const bf16x8*>(vt + r1 * 128 + swz(r1, 64 * g + 16 * hi + 32));
      o0 = mfma32(pa0, v00, o0);
      o0 = mfma32(pa1, v01, o0);
      o1 = mfma32(pa0, v10, o1);
      o1 = mfma32(pa1, v11, o1);
    }

    // ---- write-late into the other buffer; single barrier per tile --------
    if (t + 1 < NT) {
      char* kb_ = kv_lds[cur ^ 1][0]; char* vb_ = kv_lds[cur ^ 1][1];
      *reinterpret_cast<bf16x8*>(kb_ + kr0 * 128 + swz(kr0, ks0 * 16)) = kreg0;
      *reinterpret_cast<bf16x8*>(kb_ + kr1 * 128 + swz(kr1, ks1 * 16)) = kreg1;
      *reinterpret_cast<bf16x8*>(vb_ + kr0 * 128 + swz(kr0, ks0 * 16)) = vreg0;
      *reinterpret_cast<bf16x8*>(vb_ + kr1 * 128 + swz(kr1, ks1 * 16)) = vreg1;
    }
    __syncthreads();
  }

  // ---- epilogue: l-broadcast via LDS, normalize, write --------------------
  float ls = lacc[0] + lacc[1] + lacc[2] + lacc[3];
  ls += __shfl_xor(ls, 32, 64);
  if (hi == 0) lsum_lds[wv][l32] = ls;
  __syncthreads();
  f32x4 linv[4];
#pragma unroll
  for (int g = 0; g < 4; ++g) {
    f32x4 t = *reinterpret_cast<const f32x4*>(&lsum_lds[wv][8 * g + 4 * hi]);
#pragma unroll
    for (int j = 0; j < 4; ++j) linv[g][j] = 1.0f / t[j];
  }
  bf16* aop = AO + ((size_t)b * SEQ + qb) * DIMV + h * HDIM + l32;
#pragma unroll
  for (int r = 0; r < 16; ++r) {
    const int q = (r & 3) + 8 * (r >> 2) + 4 * hi;
    const float inv = linv[r >> 2][r & 3];
    aop[(size_t)q * DIMV]      = (bf16)(o0[r] * inv);
    aop[(size_t)q * DIMV + 32] = (bf16)(o1[r] * inv);
  }
}

// ---------------------------------------------------------------------------
// Kernel 3: y = AO @ Wproj + bproj + x  -> d_out (fp32)
// ---------------------------------------------------------------------------
__global__ __launch_bounds__(256) void gemm2_proj(
    const bf16* __restrict__ AO, const bf16* __restrict__ WT,
    const float* __restrict__ bproj, const float* __restrict__ x,
    float* __restrict__ Y) {
  const int tid = threadIdx.x;
  const int wave = tid >> 6, lane = tid & 63;
  const int l16 = lane & 15, lg = lane >> 4;
  const int Mbase = blockIdx.x * 128 + (wave >> 1) * 64;
  const int Nbase = blockIdx.y * 128 + (wave & 1) * 64;

  f32x4 acc[4][4] = {};
  for (int k0 = 0; k0 < DIMV; k0 += 32) {
    const int kb = k0 + lg * 8;
    bf16x8 af[4], bfr[4];
#pragma unroll
    for (int r = 0; r < 4; ++r) {
      af[r] = *reinterpret_cast<const bf16x8*>(
          AO + (size_t)(Mbase + r * 16 + l16) * DIMV + kb);
      bfr[r] = *reinterpret_cast<const bf16x8*>(
          WT + (size_t)(Nbase + r * 16 + l16) * DIMV + kb);
    }
#pragma unroll
    for (int mr = 0; mr < 4; ++mr)
#pragma unroll
      for (int nr = 0; nr < 4; ++nr)
        acc[mr][nr] = mfma16(af[mr], bfr[nr], acc[mr][nr]);
  }
#pragma unroll
  for (int mr = 0; mr < 4; ++mr)
#pragma unroll
    for (int nr = 0; nr < 4; ++nr)
#pragma unroll
      for (int j = 0; j < 4; ++j) {
        const int n = Nbase + nr * 16 + l16;
        const int m = Mbase + mr * 16 + lg * 4 + j;
        Y[(size_t)m * DIMV + n] = acc[mr][nr][j] + bproj[n] + x[(size_t)m * DIMV + n];
      }
}

// ---------------------------------------------------------------------------
// Kernel 4: in-place LayerNorm over rows of 512
// ---------------------------------------------------------------------------
__global__ __launch_bounds__(128) void ln_kernel(float* __restrict__ Y,
                                                 const float* __restrict__ gamma,
                                                 const float* __restrict__ beta) {
  const int row = blockIdx.x, tid = threadIdx.x;
  float* rp = Y + (size_t)row * DIMV;
  f32x4 v = *reinterpret_cast<const f32x4*>(rp + tid * 4);
  float s = v[0] + v[1] + v[2] + v[3];
  float q = v[0] * v[0] + v[1] * v[1] + v[2] * v[2] + v[3] * v[3];
#pragma unroll
  for (int off = 1; off < 64; off <<= 1) {
    s += __shfl_xor(s, off, 64);
    q += __shfl_xor(q, off, 64);
  }
  __shared__ float sh[4];
  if ((tid & 63) == 0) { sh[(tid >> 6) * 2] = s; sh[(tid >> 6) * 2 + 1] = q; }
  __syncthreads();
  const float ts = sh[0] + sh[2], tq = sh[1] + sh[3];
  const float mu = ts * (1.0f / DIMV);
  const float var = tq * (1.0f / DIMV) - mu * mu;
  const float rs = rsqrtf(var + 1e-5f);
  f32x4 ov;
#pragma unroll
  for (int i = 0; i < 4; ++i) {
    const int c = tid * 4 + i;
    ov[i] = (v[i] - mu) * rs * gamma[c] + beta[c];
  }
  *reinterpret_cast<f32x4*>(rp + tid * 4) = ov;
}

// ---------------------------------------------------------------------------
extern "C" void kernel_launch(void* const* d_in, const int* in_sizes, int n_in,
                              void* d_out, int out_size, void* d_ws, size_t ws_size,
                              hipStream_t stream) {
  const float* x      = (const float*)d_in[0];
  const int*   pmask  = (const int*)d_in[1];
  const float* Wqkv   = (const float*)d_in[2];
  const float* bqkv   = (const float*)d_in[3];
  const float* Wproj  = (const float*)d_in[4];
  const float* bproj  = (const float*)d_in[5];
  const float* gamma  = (const float*)d_in[6];
  const float* beta   = (const float*)d_in[7];
  const float* cosT   = (const float*)d_in[8];
  const float* sinT   = (const float*)d_in[9];
  float* out = (float*)d_out;

  char* ws = (char*)d_ws;
  const size_t MB = 1048576;
  bf16* WqkvT  = (bf16*)(ws);                       // 1.5 MiB
  bf16* WprojT = (bf16*)(ws + 3 * MB / 2);          // 0.5 MiB
  bf16* Q      = (bf16*)(ws + 2 * MB);              // 8 MiB
  bf16* Kd     = (bf16*)(ws + 10 * MB);             // 8 MiB
  bf16* VT     = (bf16*)(ws + 18 * MB);             // 8 MiB
  bf16* AO     = (bf16*)(ws + 26 * MB);             // 8 MiB (aliased with xb)
  bf16* xb     = AO;                                // xb dead before AO written
  float* BBias = (float*)(ws + 34 * MB);            // 32 KiB

  prep_w<<<2048, 256, 0, stream>>>(Wqkv, Wproj, x, pmask, WqkvT, WprojT, xb, BBias);
  gemm1_qkv_rope<<<dim3(M_TOT / 128, NQKV / 128), 256, 0, stream>>>(
      xb, WqkvT, bqkv, cosT, sinT, Q, Kd, VT);
  attn_kernel<<<dim3(SEQ / 128, BB_ * NH), 256, 0, stream>>>(Q, Kd, VT, BBias, AO);
  gemm2_proj<<<dim3(M_TOT / 128, DIMV / 128), 256, 0, stream>>>(AO, WprojT, bproj, x, out);
  ln_kernel<<<M_TOT, 128, 0, stream>>>(out, gamma, beta);
}